// Round 6
// baseline (3665.775 us; speedup 1.0000x reference)
//
#include <hip/hip_runtime.h>
#include <math.h>

// Problem constants
constexpr int B  = 128;
constexpr int T  = 1024;
constexpr int IN_DIM = 32;
constexpr int D  = 128;
constexpr int H  = 8;
constexpr int DH = 16;   // D/H
constexpr int L  = 2;
constexpr int U  = 34;   // int(5*ln(1025))
constexpr int FF = 512;  // 4*D

typedef __attribute__((ext_vector_type(8))) _Float16 f16x8;
typedef __attribute__((ext_vector_type(4))) float f32x4;

__device__ __forceinline__ unsigned short f2h(float x) {
  union { _Float16 h; unsigned short u; } v;
  v.h = (_Float16)x;
  return v.u;
}

// ---------------- kernels ----------------

// Transpose + f32->f16: out[n*K+k] = f16(in[k*N+n])
__global__ void k_prep(const float* __restrict__ in, unsigned short* __restrict__ out,
                       int K, int N) {
  int t = blockIdx.x * 256 + threadIdx.x;
  if (t >= K * N) return;
  int n = t / K, k = t - n * K;
  out[t] = f2h(in[(size_t)k * N + n]);
}

// h[b,t,:] = x[b,t,:] @ proj_w + proj_b + pos_enc(t,:)
__global__ __launch_bounds__(D) void k_proj(const float* __restrict__ x,
                                            const float* __restrict__ pw,
                                            const float* __restrict__ pb,
                                            float* __restrict__ h) {
  int row = blockIdx.x;            // b*T + t
  int t = row & (T - 1);
  int d = threadIdx.x;
  __shared__ float xs[IN_DIM];
  if (threadIdx.x < IN_DIM) xs[threadIdx.x] = x[(size_t)row * IN_DIM + threadIdx.x];
  __syncthreads();
  float acc = pb[d];
#pragma unroll
  for (int i = 0; i < IN_DIM; ++i) acc += xs[i] * pw[i * D + d];
  int j = d >> 1;
  float div = expf((float)(2 * j) * (-logf(10000.f) / (float)D));
  float ang = (float)t * div;
  acc += (d & 1) ? cosf(ang) : sinf(ang);
  h[(size_t)row * D + d] = acc;
}

// C_headmajor[b][h][t][dh] = (A[row=b*T+t,:] @ W)[h*16+dh]   32 rows/block (f32 core = R1-proven)
__global__ __launch_bounds__(256) void k_gemmKV(const float* __restrict__ A,
                                                const float* __restrict__ W,
                                                float* __restrict__ C) {
  __shared__ float As[32][D];
  int r0 = blockIdx.x * 32;
  for (int i = threadIdx.x; i < 32 * D; i += 256)
    As[i / D][i % D] = A[(size_t)(r0 + i / D) * D + (i % D)];
  __syncthreads();
  int d = threadIdx.x & 127;
  int half = threadIdx.x >> 7;   // 0 or 1 -> rows [half*16, +16)
  float acc[16];
#pragma unroll
  for (int r = 0; r < 16; ++r) acc[r] = 0.f;
  for (int k = 0; k < D; ++k) {
    float w = W[k * D + d];
#pragma unroll
    for (int r = 0; r < 16; ++r) acc[r] += As[half * 16 + r][k] * w;
  }
  int hcol = d >> 4, dh = d & 15;
#pragma unroll
  for (int r = 0; r < 16; ++r) {
    int row = r0 + half * 16 + r;          // b*T + t
    int b = row >> 10, t = row & (T - 1);
    C[((((size_t)b * H + hcol) * T + t) * DH) + dh] = acc[r];
  }
}

// qs[b,u,:] = h[b, idx[u], :] @ wq
__global__ __launch_bounds__(D) void k_qrow(const float* __restrict__ h,
                                            const int* __restrict__ idx,
                                            const float* __restrict__ wq,
                                            float* __restrict__ qs) {
  int bu = blockIdx.x;             // b*U + u
  int b = bu / U, u = bu - b * U;
  int t = idx[u];
  __shared__ float hs[D];
  hs[threadIdx.x] = h[((size_t)b * T + t) * D + threadIdx.x];
  __syncthreads();
  int d = threadIdx.x;
  float acc = 0.f;
  for (int k = 0; k < D; ++k) acc += hs[k] * wq[k * D + d];
  qs[(size_t)bu * D + d] = acc;
}

// Attention: one block per (b,h). K/V staged once in LDS (f16), wave-per-u.
__global__ __launch_bounds__(512) void k_attn2(const float* __restrict__ qs,
                                               const float* __restrict__ kbuf,
                                               const float* __restrict__ vbuf,
                                               float* __restrict__ ctx) {
  int gb = blockIdx.x;             // b*H + h
  int b = gb >> 3, hh = gb & 7;
  __shared__ unsigned short Kl[T][24];   // 48 KB (rows 16B-aligned)
  __shared__ unsigned short Vl[T][24];   // 48 KB
  __shared__ float ql[U][DH];
  const int tid = threadIdx.x;

  for (int i = tid; i < U * DH; i += 512) {
    int u = i >> 4, dh = i & 15;
    ql[u][dh] = qs[((size_t)b * U + u) * D + hh * DH + dh];
  }
  const float* kg = kbuf + (size_t)gb * T * DH;
  const float* vg = vbuf + (size_t)gb * T * DH;
  for (int i = tid; i < T * 4; i += 512) {
    int t = i >> 2, c = i & 3;
    float4 k4 = *(const float4*)(kg + t * DH + c * 4);
    ushort4 kp;
    kp.x = f2h(k4.x); kp.y = f2h(k4.y); kp.z = f2h(k4.z); kp.w = f2h(k4.w);
    *(ushort4*)&Kl[t][c * 4] = kp;
    float4 v4 = *(const float4*)(vg + t * DH + c * 4);
    ushort4 vp;
    vp.x = f2h(v4.x); vp.y = f2h(v4.y); vp.z = f2h(v4.z); vp.w = f2h(v4.w);
    *(ushort4*)&Vl[t][c * 4] = vp;
  }
  __syncthreads();

  const int wv = tid >> 6, lane = tid & 63;
  for (int u = wv; u < U; u += 8) {
    float q[DH];
#pragma unroll
    for (int dh = 0; dh < DH; ++dh) q[dh] = ql[u][dh];
    float sc[16];
    float m = -1e30f;
#pragma unroll
    for (int p = 0; p < 16; ++p) {
      int t = p * 64 + lane;
      f16x8 k0 = *(const f16x8*)&Kl[t][0];
      f16x8 k1 = *(const f16x8*)&Kl[t][8];
      float s = 0.f;
#pragma unroll
      for (int j = 0; j < 8; ++j) {
        s += q[j] * (float)k0[j];
        s += q[8 + j] * (float)k1[j];
      }
      s *= 0.25f;                  // 1/sqrt(16)
      sc[p] = s;
      m = fmaxf(m, s);
    }
#pragma unroll
    for (int off = 32; off; off >>= 1) m = fmaxf(m, __shfl_xor(m, off));
    float l = 0.f;
#pragma unroll
    for (int p = 0; p < 16; ++p) {
      float e = expf(sc[p] - m);
      sc[p] = e;
      l += e;
    }
#pragma unroll
    for (int off = 32; off; off >>= 1) l += __shfl_xor(l, off);
    float inv = 1.f / l;
    float part[DH];
#pragma unroll
    for (int dh = 0; dh < DH; ++dh) part[dh] = 0.f;
#pragma unroll
    for (int p = 0; p < 16; ++p) {
      int t = p * 64 + lane;
      f16x8 v0 = *(const f16x8*)&Vl[t][0];
      f16x8 v1 = *(const f16x8*)&Vl[t][8];
      float a = sc[p];
#pragma unroll
      for (int j = 0; j < 8; ++j) {
        part[j] += a * (float)v0[j];
        part[8 + j] += a * (float)v1[j];
      }
    }
#pragma unroll
    for (int dh = 0; dh < DH; ++dh)
#pragma unroll
      for (int off = 32; off; off >>= 1) part[dh] += __shfl_xor(part[dh], off);
    if (lane == 0) {
#pragma unroll
      for (int dh = 0; dh < DH; ++dh)
        ctx[((size_t)b * U + u) * D + hh * DH + dh] = part[dh] * inv;
    }
  }
}

// baseo[b,:] = (mean_u ctx[b,u,:]) @ wo + wo_b
__global__ __launch_bounds__(D) void k_base(const float* __restrict__ ctx,
                                            const float* __restrict__ wo,
                                            const float* __restrict__ wob,
                                            float* __restrict__ baseo) {
  int b = blockIdx.x, d = threadIdx.x;
  __shared__ float bc[D];
  float s = 0.f;
  for (int u = 0; u < U; ++u) s += ctx[((size_t)b * U + u) * D + d];
  bc[d] = s * (1.f / (float)U);
  __syncthreads();
  float acc = wob[d];
  for (int k = 0; k < D; ++k) acc += bc[k] * wo[k * D + d];
  baseo[(size_t)b * D + d] = acc;
}

// ctxo[b,u,:] = ctx[b,u,:] @ wo + wo_b
__global__ __launch_bounds__(D) void k_crow(const float* __restrict__ ctx,
                                            const float* __restrict__ wo,
                                            const float* __restrict__ wob,
                                            float* __restrict__ ctxo) {
  int bu = blockIdx.x, d = threadIdx.x;
  __shared__ float cs[D];
  cs[d] = ctx[(size_t)bu * D + d];
  __syncthreads();
  float acc = wob[d];
  for (int k = 0; k < D; ++k) acc += cs[k] * wo[k * D + d];
  ctxo[(size_t)bu * D + d] = acc;
}

// map[t] = u such that idx[u]==t, else -1
__global__ void k_map(const int* __restrict__ idx, int* __restrict__ map) {
  int t = blockIdx.x * 256 + threadIdx.x;
  if (t >= T) return;
  int m = -1;
  for (int u = 0; u < U; ++u)
    if (idx[u] == t) m = u;
  map[t] = m;
}

// h = LN(h + attn_out)   one block (128 thr) per row
__global__ __launch_bounds__(D) void k_ln1(float* __restrict__ h,
                                           const float* __restrict__ ctxo,
                                           const float* __restrict__ baseo,
                                           const int* __restrict__ map,
                                           const float* __restrict__ g,
                                           const float* __restrict__ bb) {
  int row = blockIdx.x;            // b*T + t
  int b = row >> 10, t = row & (T - 1);
  int d = threadIdx.x;
  int u = map[t];
  float add = (u >= 0) ? ctxo[((size_t)b * U + u) * D + d]
                       : baseo[(size_t)b * D + d];
  float y = h[(size_t)row * D + d] + add;
  __shared__ float red[2];
  float s = y;
  for (int off = 32; off; off >>= 1) s += __shfl_down(s, off);
  if ((threadIdx.x & 63) == 0) red[threadIdx.x >> 6] = s;
  __syncthreads();
  float m = (red[0] + red[1]) * (1.f / D);
  __syncthreads();
  float e = y - m;
  float v = e * e;
  for (int off = 32; off; off >>= 1) v += __shfl_down(v, off);
  if ((threadIdx.x & 63) == 0) red[threadIdx.x >> 6] = v;
  __syncthreads();
  float inv = rsqrtf((red[0] + red[1]) * (1.f / D) + 1e-5f);
  h[(size_t)row * D + d] = e * inv * g[d] + bb[d];
}

// Fused FF: phase1 = R5-verified MFMA; phase2 = MFMA from LINEAR padded f16 LDS;
// residual+LN2 = R5-verified. 16 rows/block.
constexpr int RF = 16;
__global__ __launch_bounds__(256) void k_ff2(
    const float* __restrict__ h,
    const unsigned short* __restrict__ w1t,  // [512][128] f16 (n-major)
    const float* __restrict__ b1,
    const unsigned short* __restrict__ w2t,  // [128][512] f16 (n-major)
    const float* __restrict__ b2,
    const float* __restrict__ g,
    const float* __restrict__ bb,
    float* __restrict__ hout) {
  __shared__ unsigned short hsb[RF * 128];   // swizzled f16 A (R5-verified)
  __shared__ float hs[RF][D];                // f32 residual copy
  __shared__ unsigned short g16[RF][520];    // gelu out f16, LINEAR padded
  __shared__ float ys[RF][D];
  __shared__ float mv[RF][2];

  const int tid = threadIdx.x;
  const int r0 = blockIdx.x * RF;

  // ---- stage h (R5 verbatim) ----
  {
    int c = tid;
    int m = c >> 4, kc = c & 15;
    const float* src = h + (size_t)(r0 + m) * D + kc * 8;
    float4 x0 = *(const float4*)src;
    float4 x1 = *(const float4*)(src + 4);
    *(float4*)&hs[m][kc * 8] = x0;
    *(float4*)&hs[m][kc * 8 + 4] = x1;
    f16x8 p;
    p[0] = (_Float16)x0.x; p[1] = (_Float16)x0.y;
    p[2] = (_Float16)x0.z; p[3] = (_Float16)x0.w;
    p[4] = (_Float16)x1.x; p[5] = (_Float16)x1.y;
    p[6] = (_Float16)x1.z; p[7] = (_Float16)x1.w;
    int byte = (m << 8) + (kc << 4);
    byte ^= (m & 7) << 4;
    *(f16x8*)((char*)hsb + byte) = p;
  }
  __syncthreads();

  const int wv = tid >> 6;
  const int l15 = tid & 15;
  const int lq = (tid & 63) >> 4;

  f16x8 afr[4];
#pragma unroll
  for (int ks = 0; ks < 4; ++ks) {
    int byte = (l15 << 8) + ks * 64 + (lq << 4);
    byte ^= (l15 & 7) << 4;
    afr[ks] = *(const f16x8*)((const char*)hsb + byte);
  }

  // ---- phase 1 (R5-verified): g16 = f16(gelu(hs @ w1 + b1)) ----
  for (int nt = 0; nt < 8; ++nt) {
    int n0 = wv * 128 + nt * 16;
    const unsigned short* wp = w1t + (size_t)(n0 + l15) * 128 + lq * 8;
    f32x4 acc0 = (f32x4){0.f, 0.f, 0.f, 0.f};
#pragma unroll
    for (int ks = 0; ks < 4; ++ks) {
      f16x8 bf = *(const f16x8*)(wp + ks * 32);
      acc0 = __builtin_amdgcn_mfma_f32_16x16x32_f16(afr[ks], bf, acc0, 0, 0, 0);
    }
    float bcol = b1[n0 + l15];
#pragma unroll
    for (int r = 0; r < 4; ++r) {
      int row0 = 4 * lq + r;                  // C/D: row = 4*(lane>>4)+reg
      float v0 = acc0[r] + bcol;
      v0 = 0.5f * v0 * (1.f + erff(v0 * 0.70710678118654752f));
      g16[row0][n0 + l15] = f2h(v0);          // col = lane&15 (+tile), linear
    }
  }
  __syncthreads();

  // ---- phase 2 (MFMA, linear A): C2 = G @ w2 ----
  f32x4 acc2[2];
  acc2[0] = (f32x4){0.f, 0.f, 0.f, 0.f};
  acc2[1] = (f32x4){0.f, 0.f, 0.f, 0.f};
  for (int ks = 0; ks < 16; ++ks) {
    f16x8 a = *(const f16x8*)&g16[l15][ks * 32 + lq * 8];
#pragma unroll
    for (int nt = 0; nt < 2; ++nt) {
      const unsigned short* wp2 =
          w2t + (size_t)(wv * 32 + nt * 16 + l15) * 512 + ks * 32 + lq * 8;
      f16x8 bf = *(const f16x8*)wp2;
      acc2[nt] = __builtin_amdgcn_mfma_f32_16x16x32_f16(a, bf, acc2[nt], 0, 0, 0);
    }
  }

  // ---- residual ----
#pragma unroll
  for (int nt = 0; nt < 2; ++nt) {
    int col = wv * 32 + nt * 16 + l15;
    float bc = b2[col];
#pragma unroll
    for (int r = 0; r < 4; ++r) {
      int row = 4 * lq + r;
      ys[row][col] = hs[row][col] + acc2[nt][r] + bc;
    }
  }
  __syncthreads();

  // ---- LN2 (R5-verified pattern): 16 threads per row ----
  {
    int row = tid >> 4, lane16 = tid & 15;
    float s = 0.f;
    for (int dd = lane16; dd < D; dd += 16) s += ys[row][dd];
    for (int off = 8; off; off >>= 1) s += __shfl_down(s, off, 16);
    if (lane16 == 0) mv[row][0] = s * (1.f / D);
  }
  __syncthreads();
  {
    int row = tid >> 4, lane16 = tid & 15;
    float mu = mv[row][0];
    float v2 = 0.f;
    for (int dd = lane16; dd < D; dd += 16) {
      float e = ys[row][dd] - mu;
      v2 += e * e;
    }
    for (int off = 8; off; off >>= 1) v2 += __shfl_down(v2, off, 16);
    if (lane16 == 0) mv[row][1] = rsqrtf(v2 * (1.f / D) + 1e-5f);
  }
  __syncthreads();
  for (int i = tid; i < RF * D; i += 256) {
    int r = i >> 7, dd = i & 127;
    hout[(size_t)(r0 + r) * D + dd] = (ys[r][dd] - mv[r][0]) * mv[r][1] * g[dd] + bb[dd];
  }
}

// out[b] = LN(h[b,T-1,:]) @ head_w + head_wb
__global__ __launch_bounds__(D) void k_head(const float* __restrict__ h,
                                            const float* __restrict__ g,
                                            const float* __restrict__ bb,
                                            const float* __restrict__ hw,
                                            const float* __restrict__ hwb,
                                            float* __restrict__ out) {
  int b = blockIdx.x, d = threadIdx.x;
  float y = h[((size_t)b * T + (T - 1)) * D + d];
  __shared__ float red[2];
  float s = y;
  for (int off = 32; off; off >>= 1) s += __shfl_down(s, off);
  if ((threadIdx.x & 63) == 0) red[threadIdx.x >> 6] = s;
  __syncthreads();
  float m = (red[0] + red[1]) * (1.f / D);
  __syncthreads();
  float e = y - m;
  float v = e * e;
  for (int off = 32; off; off >>= 1) v += __shfl_down(v, off);
  if ((threadIdx.x & 63) == 0) red[threadIdx.x >> 6] = v;
  __syncthreads();
  float inv = rsqrtf((red[0] + red[1]) * (1.f / D) + 1e-5f);
  __syncthreads();
  float last = e * inv * g[d] + bb[d];
  float p = last * hw[d];
  for (int off = 32; off; off >>= 1) p += __shfl_down(p, off);
  if ((threadIdx.x & 63) == 0) red[threadIdx.x >> 6] = p;
  __syncthreads();
  if (threadIdx.x == 0) out[b] = red[0] + red[1] + hwb[0];
}

// ---------------- launch ----------------

extern "C" void kernel_launch(void* const* d_in, const int* in_sizes, int n_in,
                              void* d_out, int out_size, void* d_ws, size_t ws_size,
                              hipStream_t stream) {
  const float* x       = (const float*)d_in[0];
  const int*   idx     = (const int*)d_in[1];
  const float* proj_w  = (const float*)d_in[2];
  const float* proj_b  = (const float*)d_in[3];
  const float* wq      = (const float*)d_in[4];
  const float* wk      = (const float*)d_in[5];
  const float* wv      = (const float*)d_in[6];
  const float* wo      = (const float*)d_in[7];
  const float* wo_b    = (const float*)d_in[8];
  const float* ln1_g   = (const float*)d_in[9];
  const float* ln1_b   = (const float*)d_in[10];
  const float* ff1_w   = (const float*)d_in[11];
  const float* ff1_b   = (const float*)d_in[12];
  const float* ff2_w   = (const float*)d_in[13];
  const float* ff2_b   = (const float*)d_in[14];
  const float* ln2_g   = (const float*)d_in[15];
  const float* ln2_b   = (const float*)d_in[16];
  const float* head_g  = (const float*)d_in[17];
  const float* head_bb = (const float*)d_in[18];
  const float* head_w  = (const float*)d_in[19];
  const float* head_wb = (const float*)d_in[20];
  float* out = (float*)d_out;

  float* wsf  = (float*)d_ws;
  float* h    = wsf;
  float* kbuf = h    + (size_t)B * T * D;   // head-major [B][H][T][DH]
  float* vbuf = kbuf + (size_t)B * T * D;   // head-major
  float* qs   = vbuf + (size_t)B * T * D;
  float* ctx  = qs   + (size_t)B * U * D;
  float* ctxo = ctx  + (size_t)B * U * D;
  float* baseo= ctxo + (size_t)B * U * D;
  int*   map  = (int*)(baseo + (size_t)B * D);
  // f16 FF weights live INSIDE the qs region (dead between k_attn2 and next k_qrow)
  unsigned short* w1T = (unsigned short*)qs;         // 512*128 ushorts = 128 KB
  unsigned short* w2T = w1T + 65536;                 // 128*512 ushorts = 128 KB (qs is 2.2 MB)

  k_proj<<<B * T, D, 0, stream>>>(x, proj_w, proj_b, h);

  for (int l = 0; l < L; ++l) {
    const float* wq_l = wq + (size_t)l * D * D;
    const float* wk_l = wk + (size_t)l * D * D;
    const float* wv_l = wv + (size_t)l * D * D;
    const float* wo_l = wo + (size_t)l * D * D;
    const int*   idx_l = idx + l * U;

    k_gemmKV<<<B * T / 32, 256, 0, stream>>>(h, wk_l, kbuf);
    k_gemmKV<<<B * T / 32, 256, 0, stream>>>(h, wv_l, vbuf);
    k_qrow<<<B * U, D, 0, stream>>>(h, idx_l, wq_l, qs);
    k_attn2<<<B * H, 512, 0, stream>>>(qs, kbuf, vbuf, ctx);
    k_base<<<B, D, 0, stream>>>(ctx, wo_l, wo_b + l * D, baseo);
    k_crow<<<B * U, D, 0, stream>>>(ctx, wo_l, wo_b + l * D, ctxo);
    k_map<<<(T + 255) / 256, 256, 0, stream>>>(idx_l, map);
    k_ln1<<<B * T, D, 0, stream>>>(h, ctxo, baseo, map,
                                   ln1_g + l * D, ln1_b + l * D);
    // qs is dead now -> prep this layer's FF weights into it
    k_prep<<<256, 256, 0, stream>>>(ff1_w + (size_t)l * D * FF, w1T, 128, 512);
    k_prep<<<256, 256, 0, stream>>>(ff2_w + (size_t)l * FF * D, w2T, 512, 128);
    k_ff2<<<B * T / RF, 256, 0, stream>>>(h, w1T, ff1_b + l * FF,
                                          w2T, ff2_b + l * D,
                                          ln2_g + l * D, ln2_b + l * D, h);
  }

  k_head<<<B, D, 0, stream>>>(h, head_g, head_bb, head_w, head_wb, out);
}

// Round 7
// 1578.190 us; speedup vs baseline: 2.3228x; 2.3228x over previous
//
#include <hip/hip_runtime.h>
#include <math.h>

// Problem constants
constexpr int B  = 128;
constexpr int T  = 1024;
constexpr int IN_DIM = 32;
constexpr int D  = 128;
constexpr int H  = 8;
constexpr int DH = 16;   // D/H
constexpr int L  = 2;
constexpr int U  = 34;   // int(5*ln(1025))
constexpr int FF = 512;  // 4*D

typedef __attribute__((ext_vector_type(8))) _Float16 f16x8;
typedef __attribute__((ext_vector_type(4))) float f32x4;

__device__ __forceinline__ unsigned short f2h(float x) {
  union { _Float16 h; unsigned short u; } v;
  v.h = (_Float16)x;
  return v.u;
}

// ---------------- helpers ----------------

__device__ __forceinline__ float blockMax256(float v, float* red) {
  for (int off = 32; off; off >>= 1) v = fmaxf(v, __shfl_down(v, off));
  if ((threadIdx.x & 63) == 0) red[threadIdx.x >> 6] = v;
  __syncthreads();
  v = fmaxf(fmaxf(red[0], red[1]), fmaxf(red[2], red[3]));
  __syncthreads();
  return v;
}

__device__ __forceinline__ float blockSum256(float v, float* red) {
  for (int off = 32; off; off >>= 1) v += __shfl_down(v, off);
  if ((threadIdx.x & 63) == 0) red[threadIdx.x >> 6] = v;
  __syncthreads();
  v = red[0] + red[1] + red[2] + red[3];
  __syncthreads();
  return v;
}

// ---------------- kernels ----------------

// Transpose + f32->f16: out[n*K+k] = f16(in[k*N+n])
__global__ void k_prep(const float* __restrict__ in, unsigned short* __restrict__ out,
                       int K, int N) {
  int t = blockIdx.x * 256 + threadIdx.x;
  if (t >= K * N) return;
  int n = t / K, k = t - n * K;
  out[t] = f2h(in[(size_t)k * N + n]);
}

// h[b,t,:] = x[b,t,:] @ proj_w + proj_b + pos_enc(t,:)
__global__ __launch_bounds__(D) void k_proj(const float* __restrict__ x,
                                            const float* __restrict__ pw,
                                            const float* __restrict__ pb,
                                            float* __restrict__ h) {
  int row = blockIdx.x;            // b*T + t
  int t = row & (T - 1);
  int d = threadIdx.x;
  __shared__ float xs[IN_DIM];
  if (threadIdx.x < IN_DIM) xs[threadIdx.x] = x[(size_t)row * IN_DIM + threadIdx.x];
  __syncthreads();
  float acc = pb[d];
#pragma unroll
  for (int i = 0; i < IN_DIM; ++i) acc += xs[i] * pw[i * D + d];
  int j = d >> 1;
  float div = expf((float)(2 * j) * (-logf(10000.f) / (float)D));
  float ang = (float)t * div;
  acc += (d & 1) ? cosf(ang) : sinf(ang);
  h[(size_t)row * D + d] = acc;
}

// C_headmajor[b][h][t][dh] = (A[row=b*T+t,:] @ W)[h*16+dh]   32 rows/block (f32 core = R1-proven)
__global__ __launch_bounds__(256) void k_gemmKV(const float* __restrict__ A,
                                                const float* __restrict__ W,
                                                float* __restrict__ C) {
  __shared__ float As[32][D];
  int r0 = blockIdx.x * 32;
  for (int i = threadIdx.x; i < 32 * D; i += 256)
    As[i / D][i % D] = A[(size_t)(r0 + i / D) * D + (i % D)];
  __syncthreads();
  int d = threadIdx.x & 127;
  int half = threadIdx.x >> 7;   // 0 or 1 -> rows [half*16, +16)
  float acc[16];
#pragma unroll
  for (int r = 0; r < 16; ++r) acc[r] = 0.f;
  for (int k = 0; k < D; ++k) {
    float w = W[k * D + d];
#pragma unroll
    for (int r = 0; r < 16; ++r) acc[r] += As[half * 16 + r][k] * w;
  }
  int hcol = d >> 4, dh = d & 15;
#pragma unroll
  for (int r = 0; r < 16; ++r) {
    int row = r0 + half * 16 + r;          // b*T + t
    int b = row >> 10, t = row & (T - 1);
    C[((((size_t)b * H + hcol) * T + t) * DH) + dh] = acc[r];
  }
}

// qs[b,u,:] = h[b, idx[u], :] @ wq
__global__ __launch_bounds__(D) void k_qrow(const float* __restrict__ h,
                                            const int* __restrict__ idx,
                                            const float* __restrict__ wq,
                                            float* __restrict__ qs) {
  int bu = blockIdx.x;             // b*U + u
  int b = bu / U, u = bu - b * U;
  int t = idx[u];
  __shared__ float hs[D];
  hs[threadIdx.x] = h[((size_t)b * T + t) * D + threadIdx.x];
  __syncthreads();
  int d = threadIdx.x;
  float acc = 0.f;
  for (int k = 0; k < D; ++k) acc += hs[k] * wq[k * D + d];
  qs[(size_t)bu * D + d] = acc;
}

// Attention (R5 structure + head-major K/V): one block per (b,h,u), u innermost.
__global__ __launch_bounds__(256) void k_attn3(const float* __restrict__ qs,
                                               const float* __restrict__ kbuf,
                                               const float* __restrict__ vbuf,
                                               float* __restrict__ ctx) {
  int id = blockIdx.x;             // (b*H+h)*U + u
  int u = id % U; int gb = id / U; int hh = gb & 7; int b = gb >> 3;
  __shared__ float sc[T];
  __shared__ float qv[DH];
  __shared__ float red[4];
  if (threadIdx.x < DH)
    qv[threadIdx.x] = qs[((size_t)b * U + u) * D + hh * DH + threadIdx.x];
  __syncthreads();
  const float* kg = kbuf + (size_t)gb * T * DH;
  const float* vg = vbuf + (size_t)gb * T * DH;
  float lmax = -1e30f;
  for (int t = threadIdx.x; t < T; t += 256) {
    const float* kp = kg + t * DH;
    float s = 0.f;
#pragma unroll
    for (int dh = 0; dh < DH; ++dh) s += qv[dh] * kp[dh];
    s *= 0.25f;                       // 1/sqrt(16)
    sc[t] = s;
    lmax = fmaxf(lmax, s);
  }
  float gmax = blockMax256(lmax, red);
  float lsum = 0.f;
  for (int t = threadIdx.x; t < T; t += 256) {
    float e = expf(sc[t] - gmax);
    sc[t] = e;
    lsum += e;
  }
  float gsum = blockSum256(lsum, red);
  float inv = 1.f / gsum;
  float part[DH];
#pragma unroll
  for (int dh = 0; dh < DH; ++dh) part[dh] = 0.f;
  for (int t = threadIdx.x; t < T; t += 256) {
    const float* vp = vg + t * DH;
    float a = sc[t];
#pragma unroll
    for (int dh = 0; dh < DH; ++dh) part[dh] += a * vp[dh];
  }
  for (int dh = 0; dh < DH; ++dh) {
    float tot = blockSum256(part[dh], red);
    if (threadIdx.x == 0)
      ctx[((size_t)b * U + u) * D + hh * DH + dh] = tot * inv;
  }
}

// baseo[b,:] = (mean_u ctx[b,u,:]) @ wo + wo_b
__global__ __launch_bounds__(D) void k_base(const float* __restrict__ ctx,
                                            const float* __restrict__ wo,
                                            const float* __restrict__ wob,
                                            float* __restrict__ baseo) {
  int b = blockIdx.x, d = threadIdx.x;
  __shared__ float bc[D];
  float s = 0.f;
  for (int u = 0; u < U; ++u) s += ctx[((size_t)b * U + u) * D + d];
  bc[d] = s * (1.f / (float)U);
  __syncthreads();
  float acc = wob[d];
  for (int k = 0; k < D; ++k) acc += bc[k] * wo[k * D + d];
  baseo[(size_t)b * D + d] = acc;
}

// ctxo[b,u,:] = ctx[b,u,:] @ wo + wo_b
__global__ __launch_bounds__(D) void k_crow(const float* __restrict__ ctx,
                                            const float* __restrict__ wo,
                                            const float* __restrict__ wob,
                                            float* __restrict__ ctxo) {
  int bu = blockIdx.x, d = threadIdx.x;
  __shared__ float cs[D];
  cs[d] = ctx[(size_t)bu * D + d];
  __syncthreads();
  float acc = wob[d];
  for (int k = 0; k < D; ++k) acc += cs[k] * wo[k * D + d];
  ctxo[(size_t)bu * D + d] = acc;
}

// map[t] = u such that idx[u]==t, else -1
__global__ void k_map(const int* __restrict__ idx, int* __restrict__ map) {
  int t = blockIdx.x * 256 + threadIdx.x;
  if (t >= T) return;
  int m = -1;
  for (int u = 0; u < U; ++u)
    if (idx[u] == t) m = u;
  map[t] = m;
}

// h = LN(h + attn_out)   one block (128 thr) per row
__global__ __launch_bounds__(D) void k_ln1(float* __restrict__ h,
                                           const float* __restrict__ ctxo,
                                           const float* __restrict__ baseo,
                                           const int* __restrict__ map,
                                           const float* __restrict__ g,
                                           const float* __restrict__ bb) {
  int row = blockIdx.x;            // b*T + t
  int b = row >> 10, t = row & (T - 1);
  int d = threadIdx.x;
  int u = map[t];
  float add = (u >= 0) ? ctxo[((size_t)b * U + u) * D + d]
                       : baseo[(size_t)b * D + d];
  float y = h[(size_t)row * D + d] + add;
  __shared__ float red[2];
  float s = y;
  for (int off = 32; off; off >>= 1) s += __shfl_down(s, off);
  if ((threadIdx.x & 63) == 0) red[threadIdx.x >> 6] = s;
  __syncthreads();
  float m = (red[0] + red[1]) * (1.f / D);
  __syncthreads();
  float e = y - m;
  float v = e * e;
  for (int off = 32; off; off >>= 1) v += __shfl_down(v, off);
  if ((threadIdx.x & 63) == 0) red[threadIdx.x >> 6] = v;
  __syncthreads();
  float inv = rsqrtf((red[0] + red[1]) * (1.f / D) + 1e-5f);
  h[(size_t)row * D + d] = e * inv * g[d] + bb[d];
}

// Fused FF: phase1 = R5-verified MFMA; phase2 = MFMA from LINEAR padded f16 LDS;
// residual+LN2 = R5-verified. 16 rows/block.  (R6-verified end-to-end)
constexpr int RF = 16;
__global__ __launch_bounds__(256) void k_ff2(
    const float* __restrict__ h,
    const unsigned short* __restrict__ w1t,  // [512][128] f16 (n-major)
    const float* __restrict__ b1,
    const unsigned short* __restrict__ w2t,  // [128][512] f16 (n-major)
    const float* __restrict__ b2,
    const float* __restrict__ g,
    const float* __restrict__ bb,
    float* __restrict__ hout) {
  __shared__ unsigned short hsb[RF * 128];   // swizzled f16 A (R5-verified)
  __shared__ float hs[RF][D];                // f32 residual copy
  __shared__ unsigned short g16[RF][520];    // gelu out f16, LINEAR padded
  __shared__ float ys[RF][D];
  __shared__ float mv[RF][2];

  const int tid = threadIdx.x;
  const int r0 = blockIdx.x * RF;

  // ---- stage h (R5 verbatim) ----
  {
    int c = tid;
    int m = c >> 4, kc = c & 15;
    const float* src = h + (size_t)(r0 + m) * D + kc * 8;
    float4 x0 = *(const float4*)src;
    float4 x1 = *(const float4*)(src + 4);
    *(float4*)&hs[m][kc * 8] = x0;
    *(float4*)&hs[m][kc * 8 + 4] = x1;
    f16x8 p;
    p[0] = (_Float16)x0.x; p[1] = (_Float16)x0.y;
    p[2] = (_Float16)x0.z; p[3] = (_Float16)x0.w;
    p[4] = (_Float16)x1.x; p[5] = (_Float16)x1.y;
    p[6] = (_Float16)x1.z; p[7] = (_Float16)x1.w;
    int byte = (m << 8) + (kc << 4);
    byte ^= (m & 7) << 4;
    *(f16x8*)((char*)hsb + byte) = p;
  }
  __syncthreads();

  const int wv = tid >> 6;
  const int l15 = tid & 15;
  const int lq = (tid & 63) >> 4;

  f16x8 afr[4];
#pragma unroll
  for (int ks = 0; ks < 4; ++ks) {
    int byte = (l15 << 8) + ks * 64 + (lq << 4);
    byte ^= (l15 & 7) << 4;
    afr[ks] = *(const f16x8*)((const char*)hsb + byte);
  }

  // ---- phase 1 (R5-verified): g16 = f16(gelu(hs @ w1 + b1)) ----
  for (int nt = 0; nt < 8; ++nt) {
    int n0 = wv * 128 + nt * 16;
    const unsigned short* wp = w1t + (size_t)(n0 + l15) * 128 + lq * 8;
    f32x4 acc0 = (f32x4){0.f, 0.f, 0.f, 0.f};
#pragma unroll
    for (int ks = 0; ks < 4; ++ks) {
      f16x8 bf = *(const f16x8*)(wp + ks * 32);
      acc0 = __builtin_amdgcn_mfma_f32_16x16x32_f16(afr[ks], bf, acc0, 0, 0, 0);
    }
    float bcol = b1[n0 + l15];
#pragma unroll
    for (int r = 0; r < 4; ++r) {
      int row0 = 4 * lq + r;                  // C/D: row = 4*(lane>>4)+reg
      float v0 = acc0[r] + bcol;
      v0 = 0.5f * v0 * (1.f + erff(v0 * 0.70710678118654752f));
      g16[row0][n0 + l15] = f2h(v0);          // col = lane&15 (+tile), linear
    }
  }
  __syncthreads();

  // ---- phase 2 (MFMA, linear A): C2 = G @ w2 ----
  f32x4 acc2[2];
  acc2[0] = (f32x4){0.f, 0.f, 0.f, 0.f};
  acc2[1] = (f32x4){0.f, 0.f, 0.f, 0.f};
  for (int ks = 0; ks < 16; ++ks) {
    f16x8 a = *(const f16x8*)&g16[l15][ks * 32 + lq * 8];
#pragma unroll
    for (int nt = 0; nt < 2; ++nt) {
      const unsigned short* wp2 =
          w2t + (size_t)(wv * 32 + nt * 16 + l15) * 512 + ks * 32 + lq * 8;
      f16x8 bf = *(const f16x8*)wp2;
      acc2[nt] = __builtin_amdgcn_mfma_f32_16x16x32_f16(a, bf, acc2[nt], 0, 0, 0);
    }
  }

  // ---- residual ----
#pragma unroll
  for (int nt = 0; nt < 2; ++nt) {
    int col = wv * 32 + nt * 16 + l15;
    float bc = b2[col];
#pragma unroll
    for (int r = 0; r < 4; ++r) {
      int row = 4 * lq + r;
      ys[row][col] = hs[row][col] + acc2[nt][r] + bc;
    }
  }
  __syncthreads();

  // ---- LN2 (R5-verified pattern): 16 threads per row ----
  {
    int row = tid >> 4, lane16 = tid & 15;
    float s = 0.f;
    for (int dd = lane16; dd < D; dd += 16) s += ys[row][dd];
    for (int off = 8; off; off >>= 1) s += __shfl_down(s, off, 16);
    if (lane16 == 0) mv[row][0] = s * (1.f / D);
  }
  __syncthreads();
  {
    int row = tid >> 4, lane16 = tid & 15;
    float mu = mv[row][0];
    float v2 = 0.f;
    for (int dd = lane16; dd < D; dd += 16) {
      float e = ys[row][dd] - mu;
      v2 += e * e;
    }
    for (int off = 8; off; off >>= 1) v2 += __shfl_down(v2, off, 16);
    if (lane16 == 0) mv[row][1] = rsqrtf(v2 * (1.f / D) + 1e-5f);
  }
  __syncthreads();
  for (int i = tid; i < RF * D; i += 256) {
    int r = i >> 7, dd = i & 127;
    hout[(size_t)(r0 + r) * D + dd] = (ys[r][dd] - mv[r][0]) * mv[r][1] * g[dd] + bb[dd];
  }
}

// out[b] = LN(h[b,T-1,:]) @ head_w + head_wb
__global__ __launch_bounds__(D) void k_head(const float* __restrict__ h,
                                            const float* __restrict__ g,
                                            const float* __restrict__ bb,
                                            const float* __restrict__ hw,
                                            const float* __restrict__ hwb,
                                            float* __restrict__ out) {
  int b = blockIdx.x, d = threadIdx.x;
  float y = h[((size_t)b * T + (T - 1)) * D + d];
  __shared__ float red[2];
  float s = y;
  for (int off = 32; off; off >>= 1) s += __shfl_down(s, off);
  if ((threadIdx.x & 63) == 0) red[threadIdx.x >> 6] = s;
  __syncthreads();
  float m = (red[0] + red[1]) * (1.f / D);
  __syncthreads();
  float e = y - m;
  float v = e * e;
  for (int off = 32; off; off >>= 1) v += __shfl_down(v, off);
  if ((threadIdx.x & 63) == 0) red[threadIdx.x >> 6] = v;
  __syncthreads();
  float inv = rsqrtf((red[0] + red[1]) * (1.f / D) + 1e-5f);
  __syncthreads();
  float last = e * inv * g[d] + bb[d];
  float p = last * hw[d];
  for (int off = 32; off; off >>= 1) p += __shfl_down(p, off);
  if ((threadIdx.x & 63) == 0) red[threadIdx.x >> 6] = p;
  __syncthreads();
  if (threadIdx.x == 0) out[b] = red[0] + red[1] + hwb[0];
}

// ---------------- launch ----------------

extern "C" void kernel_launch(void* const* d_in, const int* in_sizes, int n_in,
                              void* d_out, int out_size, void* d_ws, size_t ws_size,
                              hipStream_t stream) {
  const float* x       = (const float*)d_in[0];
  const int*   idx     = (const int*)d_in[1];
  const float* proj_w  = (const float*)d_in[2];
  const float* proj_b  = (const float*)d_in[3];
  const float* wq      = (const float*)d_in[4];
  const float* wk      = (const float*)d_in[5];
  const float* wv      = (const float*)d_in[6];
  const float* wo      = (const float*)d_in[7];
  const float* wo_b    = (const float*)d_in[8];
  const float* ln1_g   = (const float*)d_in[9];
  const float* ln1_b   = (const float*)d_in[10];
  const float* ff1_w   = (const float*)d_in[11];
  const float* ff1_b   = (const float*)d_in[12];
  const float* ff2_w   = (const float*)d_in[13];
  const float* ff2_b   = (const float*)d_in[14];
  const float* ln2_g   = (const float*)d_in[15];
  const float* ln2_b   = (const float*)d_in[16];
  const float* head_g  = (const float*)d_in[17];
  const float* head_bb = (const float*)d_in[18];
  const float* head_w  = (const float*)d_in[19];
  const float* head_wb = (const float*)d_in[20];
  float* out = (float*)d_out;

  float* wsf  = (float*)d_ws;
  float* h    = wsf;
  float* kbuf = h    + (size_t)B * T * D;   // head-major [B][H][T][DH]
  float* vbuf = kbuf + (size_t)B * T * D;   // head-major
  float* qs   = vbuf + (size_t)B * T * D;
  float* ctx  = qs   + (size_t)B * U * D;
  float* ctxo = ctx  + (size_t)B * U * D;
  float* baseo= ctxo + (size_t)B * U * D;
  int*   map  = (int*)(baseo + (size_t)B * D);
  // f16 FF weights live INSIDE the qs region (dead between k_attn3 and next k_qrow)
  unsigned short* w1T = (unsigned short*)qs;         // 512*128 ushorts = 128 KB
  unsigned short* w2T = w1T + 65536;                 // 128*512 ushorts = 128 KB (qs is 2.2 MB)

  k_proj<<<B * T, D, 0, stream>>>(x, proj_w, proj_b, h);

  for (int l = 0; l < L; ++l) {
    const float* wq_l = wq + (size_t)l * D * D;
    const float* wk_l = wk + (size_t)l * D * D;
    const float* wv_l = wv + (size_t)l * D * D;
    const float* wo_l = wo + (size_t)l * D * D;
    const int*   idx_l = idx + l * U;

    k_gemmKV<<<B * T / 32, 256, 0, stream>>>(h, wk_l, kbuf);
    k_gemmKV<<<B * T / 32, 256, 0, stream>>>(h, wv_l, vbuf);
    k_qrow<<<B * U, D, 0, stream>>>(h, idx_l, wq_l, qs);
    k_attn3<<<B * H * U, 256, 0, stream>>>(qs, kbuf, vbuf, ctx);
    k_base<<<B, D, 0, stream>>>(ctx, wo_l, wo_b + l * D, baseo);
    k_crow<<<B * U, D, 0, stream>>>(ctx, wo_l, wo_b + l * D, ctxo);
    k_map<<<(T + 255) / 256, 256, 0, stream>>>(idx_l, map);
    k_ln1<<<B * T, D, 0, stream>>>(h, ctxo, baseo, map,
                                   ln1_g + l * D, ln1_b + l * D);
    // qs is dead now -> prep this layer's FF weights into it
    k_prep<<<256, 256, 0, stream>>>(ff1_w + (size_t)l * D * FF, w1T, 128, 512);
    k_prep<<<256, 256, 0, stream>>>(ff2_w + (size_t)l * FF * D, w2T, 512, 128);
    k_ff2<<<B * T / RF, 256, 0, stream>>>(h, w1T, ff1_b + l * FF,
                                          w2T, ff2_b + l * D,
                                          ln2_g + l * D, ln2_b + l * D, h);
  }

  k_head<<<B, D, 0, stream>>>(h, head_g, head_bb, head_w, head_wb, out);
}

// Round 8
// 1307.022 us; speedup vs baseline: 2.8047x; 1.2075x over previous
//
#include <hip/hip_runtime.h>
#include <math.h>

// Problem constants
constexpr int B  = 128;
constexpr int T  = 1024;
constexpr int IN_DIM = 32;
constexpr int D  = 128;
constexpr int H  = 8;
constexpr int DH = 16;   // D/H
constexpr int L  = 2;
constexpr int U  = 34;   // int(5*ln(1025))
constexpr int FF = 512;  // 4*D

typedef __attribute__((ext_vector_type(8))) _Float16 f16x8;
typedef __attribute__((ext_vector_type(4))) float f32x4;

__device__ __forceinline__ unsigned short f2h(float x) {
  union { _Float16 h; unsigned short u; } v;
  v.h = (_Float16)x;
  return v.u;
}

// ---------------- helpers ----------------

__device__ __forceinline__ float blockMax256(float v, float* red) {
  for (int off = 32; off; off >>= 1) v = fmaxf(v, __shfl_down(v, off));
  if ((threadIdx.x & 63) == 0) red[threadIdx.x >> 6] = v;
  __syncthreads();
  v = fmaxf(fmaxf(red[0], red[1]), fmaxf(red[2], red[3]));
  __syncthreads();
  return v;
}

__device__ __forceinline__ float blockSum256(float v, float* red) {
  for (int off = 32; off; off >>= 1) v += __shfl_down(v, off);
  if ((threadIdx.x & 63) == 0) red[threadIdx.x >> 6] = v;
  __syncthreads();
  v = red[0] + red[1] + red[2] + red[3];
  __syncthreads();
  return v;
}

// ---------------- kernels ----------------

// Transpose + f32->f16: out[n*K+k] = f16(in[k*N+n])
__global__ void k_prep(const float* __restrict__ in, unsigned short* __restrict__ out,
                       int K, int N) {
  int t = blockIdx.x * 256 + threadIdx.x;
  if (t >= K * N) return;
  int n = t / K, k = t - n * K;
  out[t] = f2h(in[(size_t)k * N + n]);
}

// h[b,t,:] = x[b,t,:] @ proj_w + proj_b + pos_enc(t,:)
__global__ __launch_bounds__(D) void k_proj(const float* __restrict__ x,
                                            const float* __restrict__ pw,
                                            const float* __restrict__ pb,
                                            float* __restrict__ h) {
  int row = blockIdx.x;            // b*T + t
  int t = row & (T - 1);
  int d = threadIdx.x;
  __shared__ float xs[IN_DIM];
  if (threadIdx.x < IN_DIM) xs[threadIdx.x] = x[(size_t)row * IN_DIM + threadIdx.x];
  __syncthreads();
  float acc = pb[d];
#pragma unroll
  for (int i = 0; i < IN_DIM; ++i) acc += xs[i] * pw[i * D + d];
  int j = d >> 1;
  float div = expf((float)(2 * j) * (-logf(10000.f) / (float)D));
  float ang = (float)t * div;
  acc += (d & 1) ? cosf(ang) : sinf(ang);
  h[(size_t)row * D + d] = acc;
}

// Fused K,V projection via MFMA -> head-major f16 [B][H][T][DH].
// 16 rows/block; waves {0,1}=K cols {0-63,64-127}, {2,3}=V. R5-verified patterns.
__global__ __launch_bounds__(256) void k_kv_mfma2(
    const float* __restrict__ h,
    const unsigned short* __restrict__ wkt,   // [128][128] f16 (n-major)
    const unsigned short* __restrict__ wvt,
    unsigned short* __restrict__ kbuf, unsigned short* __restrict__ vbuf) {
  __shared__ unsigned short hsb[16 * 128];    // XOR-swizzled f16 (R5-verified)
  const int tid = threadIdx.x;
  const int r0 = blockIdx.x * 16;
  {
    int m = tid >> 4, kc = tid & 15;
    const float* src = h + (size_t)(r0 + m) * D + kc * 8;
    float4 x0 = *(const float4*)src;
    float4 x1 = *(const float4*)(src + 4);
    f16x8 p;
    p[0] = (_Float16)x0.x; p[1] = (_Float16)x0.y;
    p[2] = (_Float16)x0.z; p[3] = (_Float16)x0.w;
    p[4] = (_Float16)x1.x; p[5] = (_Float16)x1.y;
    p[6] = (_Float16)x1.z; p[7] = (_Float16)x1.w;
    int byte = (m << 8) + (kc << 4);
    byte ^= (m & 7) << 4;
    *(f16x8*)((char*)hsb + byte) = p;
  }
  __syncthreads();
  const int wv = tid >> 6;
  const int l15 = tid & 15;
  const int lq = (tid & 63) >> 4;
  f16x8 afr[4];
#pragma unroll
  for (int ks = 0; ks < 4; ++ks) {
    int byte = (l15 << 8) + ks * 64 + (lq << 4);
    byte ^= (l15 & 7) << 4;
    afr[ks] = *(const f16x8*)((const char*)hsb + byte);
  }
  const unsigned short* wt = (wv < 2) ? wkt : wvt;
  unsigned short* outp = (wv < 2) ? kbuf : vbuf;
  const int cw = (wv & 1) * 64;
  f32x4 acc[4];
#pragma unroll
  for (int nt = 0; nt < 4; ++nt) acc[nt] = (f32x4){0.f, 0.f, 0.f, 0.f};
#pragma unroll
  for (int nt = 0; nt < 4; ++nt) {
    const unsigned short* wp = wt + (size_t)(cw + nt * 16 + l15) * 128 + lq * 8;
#pragma unroll
    for (int ks = 0; ks < 4; ++ks) {
      f16x8 bf = *(const f16x8*)(wp + ks * 32);
      acc[nt] = __builtin_amdgcn_mfma_f32_16x16x32_f16(afr[ks], bf, acc[nt], 0, 0, 0);
    }
  }
#pragma unroll
  for (int nt = 0; nt < 4; ++nt) {
    int col = cw + nt * 16 + l15;
    int hcol = col >> 4, dh = col & 15;
#pragma unroll
    for (int r = 0; r < 4; ++r) {
      int row = r0 + 4 * lq + r;             // C/D: row = 4*(lane>>4)+reg
      int b = row >> 10, t = row & (T - 1);
      outp[(((size_t)b * H + hcol) * T + t) * DH + dh] = f2h(acc[nt][r]);
    }
  }
}

// qs[b,u,:] = h[b, idx[u], :] @ wq
__global__ __launch_bounds__(D) void k_qrow(const float* __restrict__ h,
                                            const int* __restrict__ idx,
                                            const float* __restrict__ wq,
                                            float* __restrict__ qs) {
  int bu = blockIdx.x;             // b*U + u
  int b = bu / U, u = bu - b * U;
  int t = idx[u];
  __shared__ float hs[D];
  hs[threadIdx.x] = h[((size_t)b * T + t) * D + threadIdx.x];
  __syncthreads();
  int d = threadIdx.x;
  float acc = 0.f;
  for (int k = 0; k < D; ++k) acc += hs[k] * wq[k * D + d];
  qs[(size_t)bu * D + d] = acc;
}

// Attention (R7 structure, f16 head-major K/V): one block per (b,h,u), u innermost.
__global__ __launch_bounds__(256) void k_attn3(const float* __restrict__ qs,
                                               const unsigned short* __restrict__ kbuf,
                                               const unsigned short* __restrict__ vbuf,
                                               float* __restrict__ ctx) {
  int id = blockIdx.x;             // (b*H+h)*U + u
  int u = id % U; int gb = id / U; int hh = gb & 7; int b = gb >> 3;
  __shared__ float sc[T];
  __shared__ float qv[DH];
  __shared__ float red[4];
  if (threadIdx.x < DH)
    qv[threadIdx.x] = qs[((size_t)b * U + u) * D + hh * DH + threadIdx.x];
  __syncthreads();
  const unsigned short* kg = kbuf + (size_t)gb * T * DH;
  const unsigned short* vg = vbuf + (size_t)gb * T * DH;
  float lmax = -1e30f;
  for (int t = threadIdx.x; t < T; t += 256) {
    f16x8 k0 = *(const f16x8*)(kg + t * DH);
    f16x8 k1 = *(const f16x8*)(kg + t * DH + 8);
    float s = 0.f;
#pragma unroll
    for (int j = 0; j < 8; ++j) {
      s += qv[j] * (float)k0[j];
      s += qv[8 + j] * (float)k1[j];
    }
    s *= 0.25f;                       // 1/sqrt(16)
    sc[t] = s;
    lmax = fmaxf(lmax, s);
  }
  float gmax = blockMax256(lmax, red);
  float lsum = 0.f;
  for (int t = threadIdx.x; t < T; t += 256) {
    float e = expf(sc[t] - gmax);
    sc[t] = e;
    lsum += e;
  }
  float gsum = blockSum256(lsum, red);
  float inv = 1.f / gsum;
  float part[DH];
#pragma unroll
  for (int dh = 0; dh < DH; ++dh) part[dh] = 0.f;
  for (int t = threadIdx.x; t < T; t += 256) {
    f16x8 v0 = *(const f16x8*)(vg + t * DH);
    f16x8 v1 = *(const f16x8*)(vg + t * DH + 8);
    float a = sc[t];
#pragma unroll
    for (int j = 0; j < 8; ++j) {
      part[j] += a * (float)v0[j];
      part[8 + j] += a * (float)v1[j];
    }
  }
  for (int dh = 0; dh < DH; ++dh) {
    float tot = blockSum256(part[dh], red);
    if (threadIdx.x == 0)
      ctx[((size_t)b * U + u) * D + hh * DH + dh] = tot * inv;
  }
}

// baseo[b,:] = (mean_u ctx[b,u,:]) @ wo + wo_b
__global__ __launch_bounds__(D) void k_base(const float* __restrict__ ctx,
                                            const float* __restrict__ wo,
                                            const float* __restrict__ wob,
                                            float* __restrict__ baseo) {
  int b = blockIdx.x, d = threadIdx.x;
  __shared__ float bc[D];
  float s = 0.f;
  for (int u = 0; u < U; ++u) s += ctx[((size_t)b * U + u) * D + d];
  bc[d] = s * (1.f / (float)U);
  __syncthreads();
  float acc = wob[d];
  for (int k = 0; k < D; ++k) acc += bc[k] * wo[k * D + d];
  baseo[(size_t)b * D + d] = acc;
}

// ctxo[b,u,:] = ctx[b,u,:] @ wo + wo_b
__global__ __launch_bounds__(D) void k_crow(const float* __restrict__ ctx,
                                            const float* __restrict__ wo,
                                            const float* __restrict__ wob,
                                            float* __restrict__ ctxo) {
  int bu = blockIdx.x, d = threadIdx.x;
  __shared__ float cs[D];
  cs[d] = ctx[(size_t)bu * D + d];
  __syncthreads();
  float acc = wob[d];
  for (int k = 0; k < D; ++k) acc += cs[k] * wo[k * D + d];
  ctxo[(size_t)bu * D + d] = acc;
}

// map[t] = u such that idx[u]==t, else -1
__global__ void k_map(const int* __restrict__ idx, int* __restrict__ map) {
  int t = blockIdx.x * 256 + threadIdx.x;
  if (t >= T) return;
  int m = -1;
  for (int u = 0; u < U; ++u)
    if (idx[u] == t) m = u;
  map[t] = m;
}

// h = LN(h + attn_out)   one block (128 thr) per row
__global__ __launch_bounds__(D) void k_ln1(float* __restrict__ h,
                                           const float* __restrict__ ctxo,
                                           const float* __restrict__ baseo,
                                           const int* __restrict__ map,
                                           const float* __restrict__ g,
                                           const float* __restrict__ bb) {
  int row = blockIdx.x;            // b*T + t
  int b = row >> 10, t = row & (T - 1);
  int d = threadIdx.x;
  int u = map[t];
  float add = (u >= 0) ? ctxo[((size_t)b * U + u) * D + d]
                       : baseo[(size_t)b * D + d];
  float y = h[(size_t)row * D + d] + add;
  __shared__ float red[2];
  float s = y;
  for (int off = 32; off; off >>= 1) s += __shfl_down(s, off);
  if ((threadIdx.x & 63) == 0) red[threadIdx.x >> 6] = s;
  __syncthreads();
  float m = (red[0] + red[1]) * (1.f / D);
  __syncthreads();
  float e = y - m;
  float v = e * e;
  for (int off = 32; off; off >>= 1) v += __shfl_down(v, off);
  if ((threadIdx.x & 63) == 0) red[threadIdx.x >> 6] = v;
  __syncthreads();
  float inv = rsqrtf((red[0] + red[1]) * (1.f / D) + 1e-5f);
  h[(size_t)row * D + d] = e * inv * g[d] + bb[d];
}

// Fused FF (R6/R7-verified end-to-end). 16 rows/block.
constexpr int RF = 16;
__global__ __launch_bounds__(256) void k_ff2(
    const float* __restrict__ h,
    const unsigned short* __restrict__ w1t,  // [512][128] f16 (n-major)
    const float* __restrict__ b1,
    const unsigned short* __restrict__ w2t,  // [128][512] f16 (n-major)
    const float* __restrict__ b2,
    const float* __restrict__ g,
    const float* __restrict__ bb,
    float* __restrict__ hout) {
  __shared__ unsigned short hsb[RF * 128];   // swizzled f16 A (R5-verified)
  __shared__ float hs[RF][D];                // f32 residual copy
  __shared__ unsigned short g16[RF][520];    // gelu out f16, LINEAR padded
  __shared__ float ys[RF][D];
  __shared__ float mv[RF][2];

  const int tid = threadIdx.x;
  const int r0 = blockIdx.x * RF;

  // ---- stage h (R5 verbatim) ----
  {
    int c = tid;
    int m = c >> 4, kc = c & 15;
    const float* src = h + (size_t)(r0 + m) * D + kc * 8;
    float4 x0 = *(const float4*)src;
    float4 x1 = *(const float4*)(src + 4);
    *(float4*)&hs[m][kc * 8] = x0;
    *(float4*)&hs[m][kc * 8 + 4] = x1;
    f16x8 p;
    p[0] = (_Float16)x0.x; p[1] = (_Float16)x0.y;
    p[2] = (_Float16)x0.z; p[3] = (_Float16)x0.w;
    p[4] = (_Float16)x1.x; p[5] = (_Float16)x1.y;
    p[6] = (_Float16)x1.z; p[7] = (_Float16)x1.w;
    int byte = (m << 8) + (kc << 4);
    byte ^= (m & 7) << 4;
    *(f16x8*)((char*)hsb + byte) = p;
  }
  __syncthreads();

  const int wv = tid >> 6;
  const int l15 = tid & 15;
  const int lq = (tid & 63) >> 4;

  f16x8 afr[4];
#pragma unroll
  for (int ks = 0; ks < 4; ++ks) {
    int byte = (l15 << 8) + ks * 64 + (lq << 4);
    byte ^= (l15 & 7) << 4;
    afr[ks] = *(const f16x8*)((const char*)hsb + byte);
  }

  // ---- phase 1 (R5-verified): g16 = f16(gelu(hs @ w1 + b1)) ----
  for (int nt = 0; nt < 8; ++nt) {
    int n0 = wv * 128 + nt * 16;
    const unsigned short* wp = w1t + (size_t)(n0 + l15) * 128 + lq * 8;
    f32x4 acc0 = (f32x4){0.f, 0.f, 0.f, 0.f};
#pragma unroll
    for (int ks = 0; ks < 4; ++ks) {
      f16x8 bf = *(const f16x8*)(wp + ks * 32);
      acc0 = __builtin_amdgcn_mfma_f32_16x16x32_f16(afr[ks], bf, acc0, 0, 0, 0);
    }
    float bcol = b1[n0 + l15];
#pragma unroll
    for (int r = 0; r < 4; ++r) {
      int row0 = 4 * lq + r;                  // C/D: row = 4*(lane>>4)+reg
      float v0 = acc0[r] + bcol;
      v0 = 0.5f * v0 * (1.f + erff(v0 * 0.70710678118654752f));
      g16[row0][n0 + l15] = f2h(v0);          // col = lane&15 (+tile), linear
    }
  }
  __syncthreads();

  // ---- phase 2 (MFMA, linear A): C2 = G @ w2 ----
  f32x4 acc2[2];
  acc2[0] = (f32x4){0.f, 0.f, 0.f, 0.f};
  acc2[1] = (f32x4){0.f, 0.f, 0.f, 0.f};
  for (int ks = 0; ks < 16; ++ks) {
    f16x8 a = *(const f16x8*)&g16[l15][ks * 32 + lq * 8];
#pragma unroll
    for (int nt = 0; nt < 2; ++nt) {
      const unsigned short* wp2 =
          w2t + (size_t)(wv * 32 + nt * 16 + l15) * 512 + ks * 32 + lq * 8;
      f16x8 bf = *(const f16x8*)wp2;
      acc2[nt] = __builtin_amdgcn_mfma_f32_16x16x32_f16(a, bf, acc2[nt], 0, 0, 0);
    }
  }

  // ---- residual ----
#pragma unroll
  for (int nt = 0; nt < 2; ++nt) {
    int col = wv * 32 + nt * 16 + l15;
    float bc = b2[col];
#pragma unroll
    for (int r = 0; r < 4; ++r) {
      int row = 4 * lq + r;
      ys[row][col] = hs[row][col] + acc2[nt][r] + bc;
    }
  }
  __syncthreads();

  // ---- LN2 (R5-verified pattern): 16 threads per row ----
  {
    int row = tid >> 4, lane16 = tid & 15;
    float s = 0.f;
    for (int dd = lane16; dd < D; dd += 16) s += ys[row][dd];
    for (int off = 8; off; off >>= 1) s += __shfl_down(s, off, 16);
    if (lane16 == 0) mv[row][0] = s * (1.f / D);
  }
  __syncthreads();
  {
    int row = tid >> 4, lane16 = tid & 15;
    float mu = mv[row][0];
    float v2 = 0.f;
    for (int dd = lane16; dd < D; dd += 16) {
      float e = ys[row][dd] - mu;
      v2 += e * e;
    }
    for (int off = 8; off; off >>= 1) v2 += __shfl_down(v2, off, 16);
    if (lane16 == 0) mv[row][1] = rsqrtf(v2 * (1.f / D) + 1e-5f);
  }
  __syncthreads();
  for (int i = tid; i < RF * D; i += 256) {
    int r = i >> 7, dd = i & 127;
    hout[(size_t)(r0 + r) * D + dd] = (ys[r][dd] - mv[r][0]) * mv[r][1] * g[dd] + bb[dd];
  }
}

// out[b] = LN(h[b,T-1,:]) @ head_w + head_wb
__global__ __launch_bounds__(D) void k_head(const float* __restrict__ h,
                                            const float* __restrict__ g,
                                            const float* __restrict__ bb,
                                            const float* __restrict__ hw,
                                            const float* __restrict__ hwb,
                                            float* __restrict__ out) {
  int b = blockIdx.x, d = threadIdx.x;
  float y = h[((size_t)b * T + (T - 1)) * D + d];
  __shared__ float red[2];
  float s = y;
  for (int off = 32; off; off >>= 1) s += __shfl_down(s, off);
  if ((threadIdx.x & 63) == 0) red[threadIdx.x >> 6] = s;
  __syncthreads();
  float m = (red[0] + red[1]) * (1.f / D);
  __syncthreads();
  float e = y - m;
  float v = e * e;
  for (int off = 32; off; off >>= 1) v += __shfl_down(v, off);
  if ((threadIdx.x & 63) == 0) red[threadIdx.x >> 6] = v;
  __syncthreads();
  float inv = rsqrtf((red[0] + red[1]) * (1.f / D) + 1e-5f);
  __syncthreads();
  float last = e * inv * g[d] + bb[d];
  float p = last * hw[d];
  for (int off = 32; off; off >>= 1) p += __shfl_down(p, off);
  if ((threadIdx.x & 63) == 0) red[threadIdx.x >> 6] = p;
  __syncthreads();
  if (threadIdx.x == 0) out[b] = red[0] + red[1] + hwb[0];
}

// ---------------- launch ----------------

extern "C" void kernel_launch(void* const* d_in, const int* in_sizes, int n_in,
                              void* d_out, int out_size, void* d_ws, size_t ws_size,
                              hipStream_t stream) {
  const float* x       = (const float*)d_in[0];
  const int*   idx     = (const int*)d_in[1];
  const float* proj_w  = (const float*)d_in[2];
  const float* proj_b  = (const float*)d_in[3];
  const float* wq      = (const float*)d_in[4];
  const float* wk      = (const float*)d_in[5];
  const float* wv      = (const float*)d_in[6];
  const float* wo      = (const float*)d_in[7];
  const float* wo_b    = (const float*)d_in[8];
  const float* ln1_g   = (const float*)d_in[9];
  const float* ln1_b   = (const float*)d_in[10];
  const float* ff1_w   = (const float*)d_in[11];
  const float* ff1_b   = (const float*)d_in[12];
  const float* ff2_w   = (const float*)d_in[13];
  const float* ff2_b   = (const float*)d_in[14];
  const float* ln2_g   = (const float*)d_in[15];
  const float* ln2_b   = (const float*)d_in[16];
  const float* head_g  = (const float*)d_in[17];
  const float* head_bb = (const float*)d_in[18];
  const float* head_w  = (const float*)d_in[19];
  const float* head_wb = (const float*)d_in[20];
  float* out = (float*)d_out;

  float* wsf  = (float*)d_ws;
  float* h    = wsf;
  float* kreg = h    + (size_t)B * T * D;   // region reused for f16 K
  float* vreg = kreg + (size_t)B * T * D;   // region reused for f16 V
  float* qs   = vreg + (size_t)B * T * D;
  float* ctx  = qs   + (size_t)B * U * D;
  float* ctxo = ctx  + (size_t)B * U * D;
  float* baseo= ctxo + (size_t)B * U * D;
  int*   map  = (int*)(baseo + (size_t)B * D);
  unsigned short* kbuf16 = (unsigned short*)kreg;    // [B][H][T][DH] f16
  unsigned short* vbuf16 = (unsigned short*)vreg;
  // f16 weight views inside the qs region (dead at the points they're used)
  unsigned short* w1T = (unsigned short*)qs;         // 512*128
  unsigned short* w2T = w1T + 65536;                 // 128*512
  unsigned short* wkT = w2T + 65536;                 // 128*128
  unsigned short* wvT = wkT + 16384;                 // 128*128  (qs region = 2.2 MB, fits)

  k_proj<<<B * T, D, 0, stream>>>(x, proj_w, proj_b, h);

  for (int l = 0; l < L; ++l) {
    const float* wq_l = wq + (size_t)l * D * D;
    const float* wo_l = wo + (size_t)l * D * D;
    const int*   idx_l = idx + l * U;

    k_prep<<<64, 256, 0, stream>>>(wk + (size_t)l * D * D, wkT, 128, 128);
    k_prep<<<64, 256, 0, stream>>>(wv + (size_t)l * D * D, wvT, 128, 128);
    k_kv_mfma2<<<B * T / 16, 256, 0, stream>>>(h, wkT, wvT, kbuf16, vbuf16);
    k_qrow<<<B * U, D, 0, stream>>>(h, idx_l, wq_l, qs);   // clobbers wkT/wvT (dead)
    k_attn3<<<B * H * U, 256, 0, stream>>>(qs, kbuf16, vbuf16, ctx);
    k_base<<<B, D, 0, stream>>>(ctx, wo_l, wo_b + l * D, baseo);
    k_crow<<<B * U, D, 0, stream>>>(ctx, wo_l, wo_b + l * D, ctxo);
    k_map<<<(T + 255) / 256, 256, 0, stream>>>(idx_l, map);
    k_ln1<<<B * T, D, 0, stream>>>(h, ctxo, baseo, map,
                                   ln1_g + l * D, ln1_b + l * D);
    // qs dead now -> prep this layer's FF weights into it
    k_prep<<<256, 256, 0, stream>>>(ff1_w + (size_t)l * D * FF, w1T, 128, 512);
    k_prep<<<256, 256, 0, stream>>>(ff2_w + (size_t)l * FF * D, w2T, 512, 128);
    k_ff2<<<B * T / RF, 256, 0, stream>>>(h, w1T, ff1_b + l * FF,
                                          w2T, ff2_b + l * D,
                                          ln2_g + l * D, ln2_b + l * D, h);
  }

  k_head<<<B, D, 0, stream>>>(h, head_g, head_bb, head_w, head_wb, out);
}